// Round 1
// baseline (296.994 us; speedup 1.0000x reference)
//
#include <hip/hip_runtime.h>
#include <stdint.h>

#define S 4096
#define E 1024
#define NH 16
#define HD 64
#define WSZ 512
#define NW 8
#define EQ 3072   // QKV fused width

typedef _Float16 f16x8 __attribute__((ext_vector_type(8)));
typedef float f32x4 __attribute__((ext_vector_type(4)));
typedef unsigned short u16;
typedef unsigned int u32;

union H8 { uint4 u4; u16 us[8]; _Float16 h[8]; f16x8 v; };

__device__ __forceinline__ u16 f2h_bits(float f) {
    union { _Float16 h; u16 u; } cv; cv.h = (_Float16)f; return cv.u;
}

// ---------------- fp32 -> fp16 convert ----------------
__global__ void cvt_f32_f16(const float* __restrict__ src, u16* __restrict__ dst, int n) {
    int i = (blockIdx.x * 256 + threadIdx.x) * 4;
    if (i < n) {
        float4 f = *(const float4*)&src[i];
        uint2 o;
        o.x = (u32)f2h_bits(f.x) | ((u32)f2h_bits(f.y) << 16);
        o.y = (u32)f2h_bits(f.z) | ((u32)f2h_bits(f.w) << 16);
        *(uint2*)&dst[i] = o;
    }
}

// ---------------- bt-GEMM: C[M][N] = A[M][K] * B[N][K]^T + bias ----------------
// A,B fp16 row-major (K contiguous). 128x128 tile, BK=32, 256 thr = 4 waves (2x2 of 64x64).
template <bool OUT_F32>
__global__ __launch_bounds__(256) void gemm_bt(
    const u16* __restrict__ A, const u16* __restrict__ B, void* __restrict__ Cout,
    const float* __restrict__ b0, const float* __restrict__ b1, const float* __restrict__ b2,
    int M, int N, int K) {
    __shared__ u16 As[128 * 32];
    __shared__ u16 Bs[128 * 32];
    const int tid = threadIdx.x;
    const int wid = tid >> 6, lid = tid & 63, quad = lid >> 4, l16 = lid & 15;
    const int wm = wid >> 1, wn = wid & 1;
    const int bm0 = blockIdx.y * 128, bn0 = blockIdx.x * 128;

    f32x4 acc[4][4] = {};
    const int sr = tid >> 2, sc = (tid & 3) * 8;

    for (int k0 = 0; k0 < K; k0 += 32) {
        __syncthreads();
        *(uint4*)&As[sr * 32 + sc]        = *(const uint4*)&A[(bm0 + sr) * K + k0 + sc];
        *(uint4*)&As[(sr + 64) * 32 + sc] = *(const uint4*)&A[(bm0 + sr + 64) * K + k0 + sc];
        *(uint4*)&Bs[sr * 32 + sc]        = *(const uint4*)&B[(bn0 + sr) * K + k0 + sc];
        *(uint4*)&Bs[(sr + 64) * 32 + sc] = *(const uint4*)&B[(bn0 + sr + 64) * K + k0 + sc];
        __syncthreads();
        f16x8 af[4], bf[4];
#pragma unroll
        for (int i = 0; i < 4; ++i) af[i] = *(const f16x8*)&As[(wm * 64 + i * 16 + l16) * 32 + quad * 8];
#pragma unroll
        for (int j = 0; j < 4; ++j) bf[j] = *(const f16x8*)&Bs[(wn * 64 + j * 16 + l16) * 32 + quad * 8];
#pragma unroll
        for (int i = 0; i < 4; ++i)
#pragma unroll
            for (int j = 0; j < 4; ++j)
                acc[i][j] = __builtin_amdgcn_mfma_f32_16x16x32_f16(af[i], bf[j], acc[i][j], 0, 0, 0);
    }

#pragma unroll
    for (int j = 0; j < 4; ++j) {
        int n = bn0 + wn * 64 + j * 16 + l16;
        float bias = (n < 1024) ? b0[n] : (n < 2048 ? b1[n - 1024] : b2[n - 2048]);
#pragma unroll
        for (int i = 0; i < 4; ++i) {
            int m0 = bm0 + wm * 64 + i * 16 + quad * 4;
#pragma unroll
            for (int r = 0; r < 4; ++r) {
                float v = acc[i][j][r] + bias;
                if (OUT_F32) ((float*)Cout)[(size_t)(m0 + r) * N + n] = v;
                else         ((u16*)Cout)[(size_t)(m0 + r) * N + n] = f2h_bits(v);
            }
        }
    }
}

// ---------------- windowed flash attention ----------------
// grid (4 qtiles, 8 windows, 16 heads); 256 thr = 4 waves, each wave 32 q-rows.
__global__ __launch_bounds__(256) void attn_win(const u16* __restrict__ QKV, u16* __restrict__ AO) {
    const int qt = blockIdx.x, w = blockIdx.y, h = blockIdx.z;
    const int tid = threadIdx.x, wid = tid >> 6, lid = tid & 63, quad = lid >> 4, l16 = lid & 15;

    // split-halves layout: row stride 32 elems (64B) -> m97-benign banking
    __shared__ u16 Ks[2][64 * 32];   // [khalf][key][d32]
    __shared__ u16 Vt[2][64 * 32];   // [keyhalf][d][key32]  (V transposed)
    __shared__ u16 Ps[4][2 * 32 * 32]; // per-wave [khalf][row][key32]

    const int qbase = w * WSZ + qt * 128 + wid * 32;
    f16x8 qf[2][2];
#pragma unroll
    for (int mt = 0; mt < 2; ++mt)
#pragma unroll
        for (int ks = 0; ks < 2; ++ks)
            qf[mt][ks] = *(const f16x8*)&QKV[(size_t)(qbase + mt * 16 + l16) * EQ + h * 64 + ks * 32 + quad * 8];

    f32x4 oacc[2][4] = {};
    float mrun[2][4], lrun[2][4];
#pragma unroll
    for (int mt = 0; mt < 2; ++mt)
#pragma unroll
        for (int r = 0; r < 4; ++r) { mrun[mt][r] = -30000.f; lrun[mt][r] = 0.f; }

    const int g0base = (w - 1) * WSZ;
    const u16 NEG1 = 0xBC00; // fp16 -1.0

    for (int c = 0; c < 24; ++c) {
        const int g0 = g0base + c * 64;
        __syncthreads();
        // stage K chunk (64 keys x 64 dims)
#pragma unroll
        for (int rep = 0; rep < 2; ++rep) {
            int ch = tid + rep * 256;
            int row = ch >> 3, cc = (ch & 7) * 8;
            int gk = g0 + row;
            uint4 val;
            if (gk >= 0 && gk < S) val = *(const uint4*)&QKV[(size_t)gk * EQ + 1024 + h * 64 + cc];
            else { u32 p = ((u32)NEG1 << 16) | NEG1; val = make_uint4(p, p, p, p); }
            *(uint4*)&Ks[cc >> 5][row * 32 + (cc & 31)] = val;
        }
        // stage V chunk transposed
        {
            int key = tid & 63, d0 = (tid >> 6) * 8;
            int gk = g0 + key;
            int kh = key >> 5, k32 = key & 31;
#pragma unroll
            for (int hh = 0; hh < 2; ++hh) {
                int d = d0 + hh * 32;
                H8 val;
                if (gk >= 0 && gk < S) val.u4 = *(const uint4*)&QKV[(size_t)gk * EQ + 2048 + h * 64 + d];
                else {
#pragma unroll
                    for (int j = 0; j < 8; ++j) val.us[j] = NEG1;
                }
#pragma unroll
                for (int j = 0; j < 8; ++j) Vt[kh][(d + j) * 32 + k32] = val.us[j];
            }
        }
        __syncthreads();

        // S = Q K^T  (per wave: 32 x 64)
        f32x4 scv[2][4];
#pragma unroll
        for (int nt = 0; nt < 4; ++nt) {
            f16x8 kf0 = *(const f16x8*)&Ks[0][(nt * 16 + l16) * 32 + quad * 8];
            f16x8 kf1 = *(const f16x8*)&Ks[1][(nt * 16 + l16) * 32 + quad * 8];
#pragma unroll
            for (int mt = 0; mt < 2; ++mt) {
                f32x4 t = {};
                t = __builtin_amdgcn_mfma_f32_16x16x32_f16(qf[mt][0], kf0, t, 0, 0, 0);
                t = __builtin_amdgcn_mfma_f32_16x16x32_f16(qf[mt][1], kf1, t, 0, 0, 0);
                scv[mt][nt] = t;
            }
        }

        // mask: key col n masked iff real && (n < rq || n > rq+1024); pads (ct==-1) stay attended
#pragma unroll
        for (int nt = 0; nt < 4; ++nt) {
            int n = c * 64 + nt * 16 + l16;     // 0..1535
            int gkey = g0base + n;
            bool real = (gkey >= 0 && gkey < S);
#pragma unroll
            for (int mt = 0; mt < 2; ++mt)
#pragma unroll
                for (int r = 0; r < 4; ++r) {
                    int rq = qt * 128 + wid * 32 + mt * 16 + quad * 4 + r; // 0..511
                    if (real && (n < rq || n > rq + 1024)) scv[mt][nt][r] = -30000.f;
                }
        }

        // online softmax update
#pragma unroll
        for (int mt = 0; mt < 2; ++mt)
#pragma unroll
            for (int r = 0; r < 4; ++r) {
                float mx = fmaxf(fmaxf(scv[mt][0][r], scv[mt][1][r]), fmaxf(scv[mt][2][r], scv[mt][3][r]));
#pragma unroll
                for (int sh = 1; sh < 16; sh <<= 1) mx = fmaxf(mx, __shfl_xor(mx, sh, 64));
                float mnew = fmaxf(mrun[mt][r], mx);
                float alpha = __expf(mrun[mt][r] - mnew);
                mrun[mt][r] = mnew;
                lrun[mt][r] *= alpha;
#pragma unroll
                for (int dt = 0; dt < 4; ++dt) oacc[mt][dt][r] *= alpha;
                float rs = 0.f;
#pragma unroll
                for (int nt = 0; nt < 4; ++nt) {
                    float p = __expf(scv[mt][nt][r] - mnew);
                    scv[mt][nt][r] = p;
                    rs += p;
                }
#pragma unroll
                for (int sh = 1; sh < 16; sh <<= 1) rs += __shfl_xor(rs, sh, 64);
                lrun[mt][r] += rs;
            }

        // P: C-layout -> LDS (A-layout round trip)
#pragma unroll
        for (int mt = 0; mt < 2; ++mt)
#pragma unroll
            for (int nt = 0; nt < 4; ++nt)
#pragma unroll
                for (int r = 0; r < 4; ++r)
                    Ps[wid][(nt >> 1) * 1024 + (mt * 16 + quad * 4 + r) * 32 + ((nt & 1) * 16 + l16)]
                        = f2h_bits(scv[mt][nt][r]);
        __syncthreads();

        // O += P V
        f16x8 vf[4][2];
#pragma unroll
        for (int dt = 0; dt < 4; ++dt) {
            vf[dt][0] = *(const f16x8*)&Vt[0][(dt * 16 + l16) * 32 + quad * 8];
            vf[dt][1] = *(const f16x8*)&Vt[1][(dt * 16 + l16) * 32 + quad * 8];
        }
#pragma unroll
        for (int mt = 0; mt < 2; ++mt) {
            f16x8 pf0 = *(const f16x8*)&Ps[wid][0 * 1024 + (mt * 16 + l16) * 32 + quad * 8];
            f16x8 pf1 = *(const f16x8*)&Ps[wid][1 * 1024 + (mt * 16 + l16) * 32 + quad * 8];
#pragma unroll
            for (int dt = 0; dt < 4; ++dt) {
                oacc[mt][dt] = __builtin_amdgcn_mfma_f32_16x16x32_f16(pf0, vf[dt][0], oacc[mt][dt], 0, 0, 0);
                oacc[mt][dt] = __builtin_amdgcn_mfma_f32_16x16x32_f16(pf1, vf[dt][1], oacc[mt][dt], 0, 0, 0);
            }
        }
    }

    // epilogue: O / l -> AO[s][64h+d] fp16
#pragma unroll
    for (int mt = 0; mt < 2; ++mt)
#pragma unroll
        for (int dt = 0; dt < 4; ++dt)
#pragma unroll
            for (int r = 0; r < 4; ++r) {
                int srow = w * WSZ + qt * 128 + wid * 32 + mt * 16 + quad * 4 + r;
                int col = h * 64 + dt * 16 + l16;
                float o = oacc[mt][dt][r] / lrun[mt][r];
                AO[(size_t)srow * E + col] = f2h_bits(o);
            }
}

// ---------------- launch ----------------
extern "C" void kernel_launch(void* const* d_in, const int* in_sizes, int n_in,
                              void* d_out, int out_size, void* d_ws, size_t ws_size,
                              hipStream_t stream) {
    const float* x  = (const float*)d_in[0];
    const float* wq = (const float*)d_in[1];
    const float* bq = (const float*)d_in[2];
    const float* wk = (const float*)d_in[3];
    const float* bk = (const float*)d_in[4];
    const float* wv = (const float*)d_in[5];
    const float* bv = (const float*)d_in[6];
    const float* wo = (const float*)d_in[7];
    const float* bo = (const float*)d_in[8];
    float* out = (float*)d_out;

    char* ws = (char*)d_ws;
    u16* XH  = (u16*)(ws);               // 4096x1024 f16: [0, 8388608)
    u16* WC  = (u16*)(ws + 8388608);     // 3072x1024 f16: [8388608, 14680064)
    u16* WOh = (u16*)(ws + 14680064);    // 1024x1024 f16: [14680064, 16777216)
    u16* QKV = (u16*)(ws + 16777216);    // 4096x3072 f16: [16777216, 41943040)
    u16* AOh = (u16*)(ws + 41943040);    // 4096x1024 f16: [41943040, 50331648)

    cvt_f32_f16<<<4096, 256, 0, stream>>>(x,  XH, 4194304);
    cvt_f32_f16<<<1024, 256, 0, stream>>>(wq, WC,            1048576);
    cvt_f32_f16<<<1024, 256, 0, stream>>>(wk, WC + 1048576,  1048576);
    cvt_f32_f16<<<1024, 256, 0, stream>>>(wv, WC + 2097152,  1048576);
    cvt_f32_f16<<<1024, 256, 0, stream>>>(wo, WOh, 1048576);

    gemm_bt<false><<<dim3(24, 32), 256, 0, stream>>>(XH, WC, QKV, bq, bk, bv, 4096, 3072, 1024);
    attn_win<<<dim3(4, 8, 16), 256, 0, stream>>>(QKV, AOh);
    gemm_bt<true><<<dim3(8, 32), 256, 0, stream>>>(AOh, WOh, out, bo, bo, bo, 4096, 1024, 1024);
}

// Round 3
// 232.765 us; speedup vs baseline: 1.2759x; 1.2759x over previous
//
#include <hip/hip_runtime.h>
#include <stdint.h>

#define S 4096
#define E 1024
#define NH 16
#define HD 64
#define WSZ 512

typedef _Float16 f16x8 __attribute__((ext_vector_type(8)));
typedef _Float16 f16x4 __attribute__((ext_vector_type(4)));
typedef float f32x4 __attribute__((ext_vector_type(4)));
typedef unsigned short u16;
typedef unsigned int u32;

__device__ __forceinline__ u16 f2h_bits(float f) {
    union { _Float16 h; u16 u; } cv; cv.h = (_Float16)f; return cv.u;
}

__device__ __forceinline__ void gld16(const u16* g, u16* l) {
    __builtin_amdgcn_global_load_lds((const __attribute__((address_space(1))) void*)g,
                                     (__attribute__((address_space(3))) void*)l, 16, 0, 0);
}

// ---------------- fused fp32->fp16 converts (5 segments, 1 launch) ----------------
struct CvtArgs {
    const float* s[5];
    u16* d[5];
    int n[5];
};
__global__ void cvt5(CvtArgs a) {
    int seg = blockIdx.y;
    const float* __restrict__ s = a.s[seg];
    u16* __restrict__ d = a.d[seg];
    int n = a.n[seg];
    for (int i = (blockIdx.x * 256 + threadIdx.x) * 4; i < n; i += gridDim.x * 1024) {
        float4 f = *(const float4*)&s[i];
        uint2 o;
        o.x = (u32)f2h_bits(f.x) | ((u32)f2h_bits(f.y) << 16);
        o.y = (u32)f2h_bits(f.z) | ((u32)f2h_bits(f.w) << 16);
        *(uint2*)&d[i] = o;
    }
}

// ---------------- bt-GEMM: C[M][N] = A[M][K]*B[N][K]^T + bias ----------------
// MODE 0: QKV gemm. n<2048 -> f16 OutQK stride 2048. n>=2048 -> V^T f16 OutVT[n-2048][4096].
// MODE 1: f32 OutF stride N, bias b0.
template <int MODE>
__global__ __launch_bounds__(256) void gemm_bt(
    const u16* __restrict__ A, const u16* __restrict__ B,
    u16* __restrict__ OutQK, u16* __restrict__ OutVT, float* __restrict__ OutF,
    const float* __restrict__ b0, const float* __restrict__ b1, const float* __restrict__ b2,
    int M, int N, int K) {
    __shared__ __align__(16) u16 As[128 * 32];
    __shared__ __align__(16) u16 Bs[128 * 32];
    const int tid = threadIdx.x;
    const int wid = tid >> 6, lid = tid & 63, quad = lid >> 4, l16 = lid & 15;
    const int wm = wid >> 1, wn = wid & 1;
    const int bm0 = blockIdx.y * 128, bn0 = blockIdx.x * 128;

    f32x4 acc[4][4] = {};
    const int sr = tid >> 2, sc = (tid & 3) * 8;   // LDS dest == tid*16B (lane-linear)

    for (int k0 = 0; k0 < K; k0 += 32) {
        __syncthreads();
        gld16(&A[(size_t)(bm0 + sr) * K + k0 + sc],      &As[tid * 8]);
        gld16(&A[(size_t)(bm0 + sr + 64) * K + k0 + sc], &As[2048 + tid * 8]);
        gld16(&B[(size_t)(bn0 + sr) * K + k0 + sc],      &Bs[tid * 8]);
        gld16(&B[(size_t)(bn0 + sr + 64) * K + k0 + sc], &Bs[2048 + tid * 8]);
        __syncthreads();
        f16x8 af[4], bf[4];
#pragma unroll
        for (int i = 0; i < 4; ++i) af[i] = *(const f16x8*)&As[(wm * 64 + i * 16 + l16) * 32 + quad * 8];
#pragma unroll
        for (int j = 0; j < 4; ++j) bf[j] = *(const f16x8*)&Bs[(wn * 64 + j * 16 + l16) * 32 + quad * 8];
#pragma unroll
        for (int i = 0; i < 4; ++i)
#pragma unroll
            for (int j = 0; j < 4; ++j)
                acc[i][j] = __builtin_amdgcn_mfma_f32_16x16x32_f16(af[i], bf[j], acc[i][j], 0, 0, 0);
    }

    const bool isV = (MODE == 0) && (bn0 >= 2048);   // block-uniform
#pragma unroll
    for (int j = 0; j < 4; ++j) {
        int n = bn0 + wn * 64 + j * 16 + l16;
        float bias;
        if (MODE == 1) bias = b0[n];
        else bias = (n < 1024) ? b0[n] : (n < 2048 ? b1[n - 1024] : b2[n - 2048]);
#pragma unroll
        for (int i = 0; i < 4; ++i) {
            int m0 = bm0 + wm * 64 + i * 16 + quad * 4;
            if (MODE == 1) {
#pragma unroll
                for (int r = 0; r < 4; ++r)
                    OutF[(size_t)(m0 + r) * N + n] = acc[i][j][r] + bias;
            } else if (!isV) {
#pragma unroll
                for (int r = 0; r < 4; ++r)
                    OutQK[(size_t)(m0 + r) * 2048 + n] = f2h_bits(acc[i][j][r] + bias);
            } else {
                u16 h0 = f2h_bits(acc[i][j][0] + bias);
                u16 h1 = f2h_bits(acc[i][j][1] + bias);
                u16 h2 = f2h_bits(acc[i][j][2] + bias);
                u16 h3 = f2h_bits(acc[i][j][3] + bias);
                uint2 pk;
                pk.x = (u32)h0 | ((u32)h1 << 16);
                pk.y = (u32)h2 | ((u32)h3 << 16);
                *(uint2*)&OutVT[(size_t)(n - 2048) * 4096 + m0] = pk;
            }
        }
    }
}

// ---------------- windowed flash attention, S^T formulation ----------------
// grid (4 qtiles, 8 windows, 16 heads); 256 thr = 4 waves, each wave 32 q-rows.
// S^T = K*Q^T via mfma (A=K, B=Q): D-layout = A-operand layout of 16x16x16 -> P feeds PV in regs.
__global__ __launch_bounds__(256) void attn_win(const u16* __restrict__ QK, const u16* __restrict__ VT,
                                                u16* __restrict__ AO) {
    const int qt = blockIdx.x, w = blockIdx.y, h = blockIdx.z;
    const int tid = threadIdx.x, wid = tid >> 6, lid = tid & 63, quad = lid >> 4, l16 = lid & 15;

    __shared__ __align__(16) u16 Ks[2][64 * 32];   // [d-half][key][d32]
    __shared__ __align__(16) u16 Vt[2][64 * 36];   // [key-half][d][key32 + pad4]

    // Q frags (B-operand): B[n=q=l16][k=d = half*32 + quad*8 + j]
    const int qrow0 = w * WSZ + qt * 128 + wid * 32;
    f16x8 qf[2][2];
#pragma unroll
    for (int mt = 0; mt < 2; ++mt)
#pragma unroll
        for (int ks = 0; ks < 2; ++ks)
            qf[mt][ks] = *(const f16x8*)&QK[(size_t)(qrow0 + mt * 16 + l16) * 2048 + h * 64 + ks * 32 + quad * 8];

    f32x4 oacc[2][4] = {};
    float mrun[2] = {-30000.f, -30000.f};  // per q (= l16)
    float lsum[2] = {0.f, 0.f};            // per-lane partial (this quad's keys)

    const int g0base = (w - 1) * WSZ;
    const int rqw = qt * 128 + wid * 32 + l16;
    const u16 NEG1 = 0xBC00; // fp16 -1.0

    for (int c = 0; c < 24; ++c) {
        const int g0 = g0base + c * 64;
        const bool pad_chunk = (g0 < 0) || (g0 >= S);
        const bool band = (c * 64 + 63 >= qt * 128) && (c * 64 <= qt * 128 + 1151);
        if (!(pad_chunk || band)) continue;           // block-uniform skip
        const bool interior = (g0 >= 0) && (g0 + 64 <= S);

        __syncthreads();
        if (interior) {
            // K via async global->LDS (lane-linear dest): key = wid*16 + (lid>>2), d = kh*32 + (lid&3)*8
#pragma unroll
            for (int kh = 0; kh < 2; ++kh) {
                const u16* gp = QK + (size_t)(g0 + wid * 16 + (lid >> 2)) * 2048 + 1024 + h * 64 + kh * 32 + (lid & 3) * 8;
                gld16(gp, &Ks[0][0] + (kh * 4 + wid) * 512 + lid * 8);
            }
            // V from VT (already transposed in global): vector load + ds_write_b64
            {
                int d = tid >> 2, k0 = (tid & 3) * 16;
                const u16* vg = VT + (size_t)(h * 64 + d) * 4096 + g0 + k0;
                uint4 va = *(const uint4*)vg;
                uint4 vb = *(const uint4*)(vg + 8);
                int kh = k0 >> 5, k32 = k0 & 31;
                u16* vp = &Vt[kh][d * 36 + k32];
                *(uint2*)(vp)      = make_uint2(va.x, va.y);
                *(uint2*)(vp + 4)  = make_uint2(va.z, va.w);
                *(uint2*)(vp + 8)  = make_uint2(vb.x, vb.y);
                *(uint2*)(vp + 12) = make_uint2(vb.z, vb.w);
            }
        } else {
            // boundary: predicated staging with -1.0 pad
#pragma unroll
            for (int rep = 0; rep < 2; ++rep) {
                int ch = tid + rep * 256;
                int row = ch >> 3, cc = (ch & 7) * 8;
                int gk = g0 + row;
                uint4 val;
                if (gk >= 0 && gk < S) val = *(const uint4*)&QK[(size_t)gk * 2048 + 1024 + h * 64 + cc];
                else { u32 p = ((u32)NEG1 << 16) | NEG1; val = make_uint4(p, p, p, p); }
                *(uint4*)&Ks[cc >> 5][row * 32 + (cc & 31)] = val;
            }
            {
                int d = tid >> 2, k0 = (tid & 3) * 16;
                int kh = k0 >> 5, k32 = k0 & 31;
                const u16* vrow = VT + (size_t)(h * 64 + d) * 4096;
#pragma unroll
                for (int grp = 0; grp < 4; ++grp) {
                    u16 tmp[4];
#pragma unroll
                    for (int j = 0; j < 4; ++j) {
                        int key = g0 + k0 + grp * 4 + j;
                        tmp[j] = (key >= 0 && key < S) ? vrow[key] : NEG1;
                    }
                    *(uint2*)&Vt[kh][d * 36 + k32 + grp * 4] =
                        make_uint2((u32)tmp[0] | ((u32)tmp[1] << 16), (u32)tmp[2] | ((u32)tmp[3] << 16));
                }
            }
        }
        __syncthreads();

        // K A-frags: A[m=key=nt*16+l16][k=d]
        f16x8 kf[4][2];
#pragma unroll
        for (int nt = 0; nt < 4; ++nt) {
            kf[nt][0] = *(const f16x8*)&Ks[0][(nt * 16 + l16) * 32 + quad * 8];
            kf[nt][1] = *(const f16x8*)&Ks[1][(nt * 16 + l16) * 32 + quad * 8];
        }
        // V B-frags: B[n=d=dt*16+l16][k=key = nt*16+quad*4+j]
        f16x4 vf[4][4];
#pragma unroll
        for (int dt = 0; dt < 4; ++dt)
#pragma unroll
            for (int nt = 0; nt < 4; ++nt)
                vf[dt][nt] = *(const f16x4*)&Vt[nt >> 1][(dt * 16 + l16) * 36 + (nt & 1) * 16 + quad * 4];

#pragma unroll
        for (int mt = 0; mt < 2; ++mt) {
            // S^T tiles: lane holds S^T[key=nt*16+quad*4+r][q=l16]
            f32x4 sc[4];
#pragma unroll
            for (int nt = 0; nt < 4; ++nt) {
                f32x4 t = {};
                t = __builtin_amdgcn_mfma_f32_16x16x32_f16(kf[nt][0], qf[mt][0], t, 0, 0, 0);
                t = __builtin_amdgcn_mfma_f32_16x16x32_f16(kf[nt][1], qf[mt][1], t, 0, 0, 0);
                sc[nt] = t;
            }
            const int rqm = rqw + mt * 16;
            float mloc = mrun[mt];
#pragma unroll
            for (int nt = 0; nt < 4; ++nt)
#pragma unroll
                for (int r = 0; r < 4; ++r) {
                    int n = c * 64 + nt * 16 + quad * 4 + r;
                    int gkey = g0base + n;
                    bool real = ((unsigned)gkey < (unsigned)S);
                    bool masked = real && (n < rqm || n > rqm + 1024);
                    if (masked) sc[nt][r] = -30000.f;
                    mloc = fmaxf(mloc, sc[nt][r]);
                }
            mloc = fmaxf(mloc, __shfl_xor(mloc, 16, 64));
            mloc = fmaxf(mloc, __shfl_xor(mloc, 32, 64));
            float alpha = __expf(mrun[mt] - mloc);
            mrun[mt] = mloc;
            float ls = 0.f;
            f16x4 pf[4];
#pragma unroll
            for (int nt = 0; nt < 4; ++nt)
#pragma unroll
                for (int r = 0; r < 4; ++r) {
                    float p = __expf(sc[nt][r] - mloc);
                    ls += p;
                    pf[nt][r] = (_Float16)p;
                }
            lsum[mt] = lsum[mt] * alpha + ls;
            // broadcast alpha to D-layout rows (q = quad*4+r)
            float ao[4];
#pragma unroll
            for (int r = 0; r < 4; ++r) ao[r] = __shfl(alpha, quad * 4 + r, 64);
#pragma unroll
            for (int dt = 0; dt < 4; ++dt)
#pragma unroll
                for (int r = 0; r < 4; ++r) oacc[mt][dt][r] *= ao[r];
            // PV: O[q][d] += P * V  (P direct from regs as A-operand of 16x16x16)
#pragma unroll
            for (int nt = 0; nt < 4; ++nt)
#pragma unroll
                for (int dt = 0; dt < 4; ++dt)
                    oacc[mt][dt] = __builtin_amdgcn_mfma_f32_16x16x16f16(pf[nt], vf[dt][nt], oacc[mt][dt], 0, 0, 0);
        }
    }

    // epilogue: reduce l across quads, normalize, store f16
#pragma unroll
    for (int mt = 0; mt < 2; ++mt) {
        float lt = lsum[mt];
        lt += __shfl_xor(lt, 16, 64);
        lt += __shfl_xor(lt, 32, 64);
        float linv = 1.f / lt;          // per q = l16
        float lrec[4];
#pragma unroll
        for (int r = 0; r < 4; ++r) lrec[r] = __shfl(linv, quad * 4 + r, 64);
#pragma unroll
        for (int dt = 0; dt < 4; ++dt)
#pragma unroll
            for (int r = 0; r < 4; ++r) {
                int srow = w * WSZ + qt * 128 + wid * 32 + mt * 16 + quad * 4 + r;
                int col = h * 64 + dt * 16 + l16;
                AO[(size_t)srow * E + col] = f2h_bits(oacc[mt][dt][r] * lrec[r]);
            }
    }
}

// ---------------- launch ----------------
extern "C" void kernel_launch(void* const* d_in, const int* in_sizes, int n_in,
                              void* d_out, int out_size, void* d_ws, size_t ws_size,
                              hipStream_t stream) {
    const float* x  = (const float*)d_in[0];
    const float* wq = (const float*)d_in[1];
    const float* bq = (const float*)d_in[2];
    const float* wk = (const float*)d_in[3];
    const float* bk = (const float*)d_in[4];
    const float* wv = (const float*)d_in[5];
    const float* bv = (const float*)d_in[6];
    const float* wo = (const float*)d_in[7];
    const float* bo = (const float*)d_in[8];
    float* out = (float*)d_out;

    char* ws = (char*)d_ws;
    u16* XH  = (u16*)(ws);               // 4096x1024 f16   [0, 8388608)
    u16* WC  = (u16*)(ws + 8388608);     // 3072x1024 f16   [8388608, 14680064)
    u16* WOh = (u16*)(ws + 14680064);    // 1024x1024 f16   [14680064, 16777216)
    u16* QK  = (u16*)(ws + 16777216);    // 4096x2048 f16   [16777216, 33554432)
    u16* VTg = (u16*)(ws + 33554432);    // 1024x4096 f16   [33554432, 41943040)
    u16* AOh = (u16*)(ws + 41943040);    // 4096x1024 f16   [41943040, 50331648)

    CvtArgs ca;
    ca.s[0] = x;  ca.d[0] = XH;            ca.n[0] = 4194304;
    ca.s[1] = wq; ca.d[1] = WC;            ca.n[1] = 1048576;
    ca.s[2] = wk; ca.d[2] = WC + 1048576;  ca.n[2] = 1048576;
    ca.s[3] = wv; ca.d[3] = WC + 2097152;  ca.n[3] = 1048576;
    ca.s[4] = wo; ca.d[4] = WOh;           ca.n[4] = 1048576;
    cvt5<<<dim3(1024, 5), 256, 0, stream>>>(ca);

    gemm_bt<0><<<dim3(24, 32), 256, 0, stream>>>(XH, WC, QK, VTg, nullptr, bq, bk, bv, 4096, 3072, 1024);
    attn_win<<<dim3(4, 8, 16), 256, 0, stream>>>(QK, VTg, AOh);
    gemm_bt<1><<<dim3(8, 32), 256, 0, stream>>>(AOh, WOh, nullptr, nullptr, out, bo, bo, bo, 4096, 1024, 1024);
}

// Round 4
// 202.006 us; speedup vs baseline: 1.4702x; 1.1523x over previous
//
#include <hip/hip_runtime.h>
#include <stdint.h>

#define S 4096
#define E 1024
#define NH 16
#define HD 64
#define WSZ 512

typedef _Float16 f16x8 __attribute__((ext_vector_type(8)));
typedef _Float16 f16x4 __attribute__((ext_vector_type(4)));
typedef float f32x4 __attribute__((ext_vector_type(4)));
typedef unsigned short u16;
typedef unsigned int u32;

__device__ __forceinline__ u16 f2h_bits(float f) {
    union { _Float16 h; u16 u; } cv; cv.h = (_Float16)f; return cv.u;
}

__device__ __forceinline__ void gld16(const u16* g, u16* l) {
    __builtin_amdgcn_global_load_lds((const __attribute__((address_space(1))) void*)g,
                                     (__attribute__((address_space(3))) void*)l, 16, 0, 0);
}

// ---------------- fused fp32->fp16 converts (5 segments, 1 launch) ----------------
struct CvtArgs {
    const float* s[5];
    u16* d[5];
    int n[5];
};
__global__ void cvt5(CvtArgs a) {
    int seg = blockIdx.y;
    const float* __restrict__ s = a.s[seg];
    u16* __restrict__ d = a.d[seg];
    int n = a.n[seg];
    for (int i = (blockIdx.x * 256 + threadIdx.x) * 4; i < n; i += gridDim.x * 1024) {
        float4 f = *(const float4*)&s[i];
        uint2 o;
        o.x = (u32)f2h_bits(f.x) | ((u32)f2h_bits(f.y) << 16);
        o.y = (u32)f2h_bits(f.z) | ((u32)f2h_bits(f.w) << 16);
        *(uint2*)&d[i] = o;
    }
}

// ---------------- QKV bt-GEMM: 128x128 tile. n<2048 -> f16 QK (stride 2048);
// n>=2048 -> V^T f16 OutVT[n-2048][4096]. ----------------
__global__ __launch_bounds__(256) void gemm_qkv(
    const u16* __restrict__ A, const u16* __restrict__ B,
    u16* __restrict__ OutQK, u16* __restrict__ OutVT,
    const float* __restrict__ b0, const float* __restrict__ b1, const float* __restrict__ b2,
    int K) {
    __shared__ __align__(16) u16 As[128 * 32];
    __shared__ __align__(16) u16 Bs[128 * 32];
    const int tid = threadIdx.x;
    const int wid = tid >> 6, lid = tid & 63, quad = lid >> 4, l16 = lid & 15;
    const int wm = wid >> 1, wn = wid & 1;
    const int bm0 = blockIdx.y * 128, bn0 = blockIdx.x * 128;

    f32x4 acc[4][4] = {};
    const int sr = tid >> 2, sc = (tid & 3) * 8;   // LDS dest == tid*16B (lane-linear)

    for (int k0 = 0; k0 < K; k0 += 32) {
        __syncthreads();
        gld16(&A[(size_t)(bm0 + sr) * K + k0 + sc],      &As[tid * 8]);
        gld16(&A[(size_t)(bm0 + sr + 64) * K + k0 + sc], &As[2048 + tid * 8]);
        gld16(&B[(size_t)(bn0 + sr) * K + k0 + sc],      &Bs[tid * 8]);
        gld16(&B[(size_t)(bn0 + sr + 64) * K + k0 + sc], &Bs[2048 + tid * 8]);
        __syncthreads();
        f16x8 af[4], bf[4];
#pragma unroll
        for (int i = 0; i < 4; ++i) af[i] = *(const f16x8*)&As[(wm * 64 + i * 16 + l16) * 32 + quad * 8];
#pragma unroll
        for (int j = 0; j < 4; ++j) bf[j] = *(const f16x8*)&Bs[(wn * 64 + j * 16 + l16) * 32 + quad * 8];
#pragma unroll
        for (int i = 0; i < 4; ++i)
#pragma unroll
            for (int j = 0; j < 4; ++j)
                acc[i][j] = __builtin_amdgcn_mfma_f32_16x16x32_f16(af[i], bf[j], acc[i][j], 0, 0, 0);
    }

    const bool isV = (bn0 >= 2048);   // block-uniform
#pragma unroll
    for (int j = 0; j < 4; ++j) {
        int n = bn0 + wn * 64 + j * 16 + l16;
        float bias = (n < 1024) ? b0[n] : (n < 2048 ? b1[n - 1024] : b2[n - 2048]);
#pragma unroll
        for (int i = 0; i < 4; ++i) {
            int m0 = bm0 + wm * 64 + i * 16 + quad * 4;
            if (!isV) {
#pragma unroll
                for (int r = 0; r < 4; ++r)
                    OutQK[(size_t)(m0 + r) * 2048 + n] = f2h_bits(acc[i][j][r] + bias);
            } else {
                u16 h0 = f2h_bits(acc[i][j][0] + bias);
                u16 h1 = f2h_bits(acc[i][j][1] + bias);
                u16 h2 = f2h_bits(acc[i][j][2] + bias);
                u16 h3 = f2h_bits(acc[i][j][3] + bias);
                uint2 pk;
                pk.x = (u32)h0 | ((u32)h1 << 16);
                pk.y = (u32)h2 | ((u32)h3 << 16);
                *(uint2*)&OutVT[(size_t)(n - 2048) * 4096 + m0] = pk;
            }
        }
    }
}

// ---------------- final proj bt-GEMM: 128(M)x64(N) tile, f32 out + bias ----------------
// grid (N/64, M/128) = (16, 32) = 512 blocks -> 2 blocks/CU, 8 waves/CU.
__global__ __launch_bounds__(256) void gemm_n64(
    const u16* __restrict__ A, const u16* __restrict__ B, float* __restrict__ OutF,
    const float* __restrict__ bias, int N, int K) {
    __shared__ __align__(16) u16 As[128 * 32];
    __shared__ __align__(16) u16 Bs[64 * 32];
    const int tid = threadIdx.x;
    const int wid = tid >> 6, lid = tid & 63, quad = lid >> 4, l16 = lid & 15;
    const int bm0 = blockIdx.y * 128, bn0 = blockIdx.x * 64;

    f32x4 acc[2][4] = {};
    const int sr = tid >> 2, sc = (tid & 3) * 8;

    for (int k0 = 0; k0 < K; k0 += 32) {
        __syncthreads();
        gld16(&A[(size_t)(bm0 + sr) * K + k0 + sc],      &As[tid * 8]);
        gld16(&A[(size_t)(bm0 + sr + 64) * K + k0 + sc], &As[2048 + tid * 8]);
        gld16(&B[(size_t)(bn0 + sr) * K + k0 + sc],      &Bs[tid * 8]);
        __syncthreads();
        f16x8 af[2], bf[4];
#pragma unroll
        for (int i = 0; i < 2; ++i) af[i] = *(const f16x8*)&As[(wid * 32 + i * 16 + l16) * 32 + quad * 8];
#pragma unroll
        for (int j = 0; j < 4; ++j) bf[j] = *(const f16x8*)&Bs[(j * 16 + l16) * 32 + quad * 8];
#pragma unroll
        for (int i = 0; i < 2; ++i)
#pragma unroll
            for (int j = 0; j < 4; ++j)
                acc[i][j] = __builtin_amdgcn_mfma_f32_16x16x32_f16(af[i], bf[j], acc[i][j], 0, 0, 0);
    }

#pragma unroll
    for (int j = 0; j < 4; ++j) {
        int n = bn0 + j * 16 + l16;
        float bv = bias[n];
#pragma unroll
        for (int i = 0; i < 2; ++i) {
            int m0 = bm0 + wid * 32 + i * 16 + quad * 4;
#pragma unroll
            for (int r = 0; r < 4; ++r)
                OutF[(size_t)(m0 + r) * N + n] = acc[i][j][r] + bv;
        }
    }
}

// ---------------- windowed flash attention, S^T formulation, 8 waves x 16 q-rows ----------------
__global__ __launch_bounds__(512, 4) void attn_win(const u16* __restrict__ QK, const u16* __restrict__ VT,
                                                   u16* __restrict__ AO) {
    const int qt = blockIdx.x, w = blockIdx.y, h = blockIdx.z;
    const int tid = threadIdx.x, wid = tid >> 6, lid = tid & 63, quad = lid >> 4, l16 = lid & 15;

    __shared__ __align__(16) u16 Ks[2][64 * 32];   // [d-half][key][d32]
    __shared__ __align__(16) u16 Vt[2][64 * 36];   // [key-half][d][key32 + pad4]

    // Q frags (B-operand): B[n=q=l16][k=d = ks*32 + quad*8 + j]
    const int qrow = w * WSZ + qt * 128 + wid * 16 + l16;
    f16x8 qf[2];
#pragma unroll
    for (int ks = 0; ks < 2; ++ks)
        qf[ks] = *(const f16x8*)&QK[(size_t)qrow * 2048 + h * 64 + ks * 32 + quad * 8];

    f32x4 oacc[4] = {};
    float mrun = -30000.f;   // per q (= l16)
    float lsum = 0.f;        // per-lane partial (this quad's keys)

    const int g0base = (w - 1) * WSZ;
    const int rqloc = qt * 128 + wid * 16 + l16;  // window-local q index of this lane
    const int rqw0 = qt * 128 + wid * 16;         // wave-uniform min q
    const u16 NEG1 = 0xBC00; // fp16 -1.0

    // staging maps (tid-based, computed once)
    const int kst = tid & 255, kkh = tid >> 8;        // K: key = kst>>2, col8 = (kst&3)*8
    const int vd = tid >> 3, vk0 = (tid & 7) * 8;     // V: d row, key group

    for (int c = 0; c < 24; ++c) {
        const int g0 = g0base + c * 64;
        const bool pad_chunk = (g0 < 0) || (g0 >= S);   // chunks are 64-aligned: all-real or all-pad
        const bool band = (c * 64 + 63 >= qt * 128) && (c * 64 <= qt * 128 + 1151);
        if (!(pad_chunk || band)) continue;             // block-uniform skip

        __syncthreads();
        if (!pad_chunk) {
            // K async global->LDS: 512 thr x 16B = 8KB
            gld16(QK + (size_t)(g0 + (kst >> 2)) * 2048 + 1024 + h * 64 + kkh * 32 + (kst & 3) * 8,
                  &Ks[0][0] + kkh * 2048 + kst * 8);
            // V from VT: vector load + 2x ds_write_b64
            {
                uint4 va = *(const uint4*)(VT + (size_t)(h * 64 + vd) * 4096 + g0 + vk0);
                u16* vp = &Vt[vk0 >> 5][vd * 36 + (vk0 & 31)];
                *(uint2*)(vp)     = make_uint2(va.x, va.y);
                *(uint2*)(vp + 4) = make_uint2(va.z, va.w);
            }
        } else {
            // pad chunk: fill with -1.0
            {
                u32 p = ((u32)NEG1 << 16) | NEG1;
                uint4 val = make_uint4(p, p, p, p);
                *(uint4*)&Ks[kkh][(kst >> 2) * 32 + (kst & 3) * 8] = val;
                u16* vp = &Vt[vk0 >> 5][vd * 36 + (vk0 & 31)];
                *(uint2*)(vp)     = make_uint2(p, p);
                *(uint2*)(vp + 4) = make_uint2(p, p);
            }
        }
        __syncthreads();

        // S^T = K * Q^T : lane holds S^T[key=nt*16+quad*4+r][q=l16]
        f32x4 sc[4];
#pragma unroll
        for (int nt = 0; nt < 4; ++nt) {
            f16x8 kf0 = *(const f16x8*)&Ks[0][(nt * 16 + l16) * 32 + quad * 8];
            f16x8 kf1 = *(const f16x8*)&Ks[1][(nt * 16 + l16) * 32 + quad * 8];
            f32x4 t = {};
            t = __builtin_amdgcn_mfma_f32_16x16x32_f16(kf0, qf[0], t, 0, 0, 0);
            t = __builtin_amdgcn_mfma_f32_16x16x32_f16(kf1, qf[1], t, 0, 0, 0);
            sc[nt] = t;
        }

        // mask only when this wave's band edge intersects the chunk (wave-uniform branch)
        const bool needs_mask = !pad_chunk &&
            ((c * 64 < rqw0 + 16) || (c * 64 + 63 > rqw0 + 1024));
        if (needs_mask) {
#pragma unroll
            for (int nt = 0; nt < 4; ++nt)
#pragma unroll
                for (int r = 0; r < 4; ++r) {
                    int n = c * 64 + nt * 16 + quad * 4 + r;
                    if (n < rqloc || n > rqloc + 1024) sc[nt][r] = -30000.f;
                }
        }

        // online softmax
        float mloc = mrun;
#pragma unroll
        for (int nt = 0; nt < 4; ++nt) {
            mloc = fmaxf(mloc, fmaxf(fmaxf(sc[nt][0], sc[nt][1]), fmaxf(sc[nt][2], sc[nt][3])));
        }
        mloc = fmaxf(mloc, __shfl_xor(mloc, 16, 64));
        mloc = fmaxf(mloc, __shfl_xor(mloc, 32, 64));
        float alpha = __expf(mrun - mloc);
        mrun = mloc;
        float ls = 0.f;
        f16x4 pf[4];
#pragma unroll
        for (int nt = 0; nt < 4; ++nt)
#pragma unroll
            for (int r = 0; r < 4; ++r) {
                float p = __expf(sc[nt][r] - mloc);
                ls += p;
                pf[nt][r] = (_Float16)p;
            }
        lsum = lsum * alpha + ls;
        // broadcast alpha to D-layout rows (q = quad*4+r)
        float ao[4];
#pragma unroll
        for (int r = 0; r < 4; ++r) ao[r] = __shfl(alpha, quad * 4 + r, 64);
#pragma unroll
        for (int dt = 0; dt < 4; ++dt)
#pragma unroll
            for (int r = 0; r < 4; ++r) oacc[dt][r] *= ao[r];

        // O += P V  (P direct from regs as A-operand of 16x16x16)
#pragma unroll
        for (int nt = 0; nt < 4; ++nt)
#pragma unroll
            for (int dt = 0; dt < 4; ++dt) {
                f16x4 vf = *(const f16x4*)&Vt[nt >> 1][(dt * 16 + l16) * 36 + (nt & 1) * 16 + quad * 4];
                oacc[dt] = __builtin_amdgcn_mfma_f32_16x16x16f16(pf[nt], vf, oacc[dt], 0, 0, 0);
            }
    }

    // epilogue: reduce l across quads, normalize, store f16
    float lt = lsum;
    lt += __shfl_xor(lt, 16, 64);
    lt += __shfl_xor(lt, 32, 64);
    float linv = 1.f / lt;          // per q = l16
    float lrec[4];
#pragma unroll
    for (int r = 0; r < 4; ++r) lrec[r] = __shfl(linv, quad * 4 + r, 64);
#pragma unroll
    for (int dt = 0; dt < 4; ++dt)
#pragma unroll
        for (int r = 0; r < 4; ++r) {
            int srow = w * WSZ + qt * 128 + wid * 16 + quad * 4 + r;
            int col = h * 64 + dt * 16 + l16;
            AO[(size_t)srow * E + col] = f2h_bits(oacc[dt][r] * lrec[r]);
        }
}

// ---------------- launch ----------------
extern "C" void kernel_launch(void* const* d_in, const int* in_sizes, int n_in,
                              void* d_out, int out_size, void* d_ws, size_t ws_size,
                              hipStream_t stream) {
    const float* x  = (const float*)d_in[0];
    const float* wq = (const float*)d_in[1];
    const float* bq = (const float*)d_in[2];
    const float* wk = (const float*)d_in[3];
    const float* bk = (const float*)d_in[4];
    const float* wv = (const float*)d_in[5];
    const float* bv = (const float*)d_in[6];
    const float* wo = (const float*)d_in[7];
    const float* bo = (const float*)d_in[8];
    float* out = (float*)d_out;

    char* ws = (char*)d_ws;
    u16* XH  = (u16*)(ws);               // 4096x1024 f16   [0, 8388608)
    u16* WC  = (u16*)(ws + 8388608);     // 3072x1024 f16   [8388608, 14680064)
    u16* WOh = (u16*)(ws + 14680064);    // 1024x1024 f16   [14680064, 16777216)
    u16* QK  = (u16*)(ws + 16777216);    // 4096x2048 f16   [16777216, 33554432)
    u16* VTg = (u16*)(ws + 33554432);    // 1024x4096 f16   [33554432, 41943040)
    u16* AOh = (u16*)(ws + 41943040);    // 4096x1024 f16   [41943040, 50331648)

    CvtArgs ca;
    ca.s[0] = x;  ca.d[0] = XH;            ca.n[0] = 4194304;
    ca.s[1] = wq; ca.d[1] = WC;            ca.n[1] = 1048576;
    ca.s[2] = wk; ca.d[2] = WC + 1048576;  ca.n[2] = 1048576;
    ca.s[3] = wv; ca.d[3] = WC + 2097152;  ca.n[3] = 1048576;
    ca.s[4] = wo; ca.d[4] = WOh;           ca.n[4] = 1048576;
    cvt5<<<dim3(1024, 5), 256, 0, stream>>>(ca);

    gemm_qkv<<<dim3(24, 32), 256, 0, stream>>>(XH, WC, QK, VTg, bq, bk, bv, 1024);
    attn_win<<<dim3(4, 8, 16), 512, 0, stream>>>(QK, VTg, AOh);
    gemm_n64<<<dim3(16, 32), 256, 0, stream>>>(AOh, WOh, out, bo, 1024, 1024);
}

// Round 5
// 198.058 us; speedup vs baseline: 1.4995x; 1.0199x over previous
//
#include <hip/hip_runtime.h>
#include <stdint.h>

#define S 4096
#define E 1024
#define NH 16
#define HD 64
#define WSZ 512

typedef _Float16 f16x8 __attribute__((ext_vector_type(8)));
typedef _Float16 f16x4 __attribute__((ext_vector_type(4)));
typedef float f32x4 __attribute__((ext_vector_type(4)));
typedef unsigned short u16;
typedef unsigned int u32;

__device__ __forceinline__ u16 f2h_bits(float f) {
    union { _Float16 h; u16 u; } cv; cv.h = (_Float16)f; return cv.u;
}

__device__ __forceinline__ void gld16(const u16* g, u16* l) {
    __builtin_amdgcn_global_load_lds((const __attribute__((address_space(1))) void*)g,
                                     (__attribute__((address_space(3))) void*)l, 16, 0, 0);
}

// ---------------- fused fp32->fp16 converts (5 segments, 1 launch) ----------------
struct CvtArgs {
    const float* s[5];
    u16* d[5];
    int n[5];
};
__global__ void cvt5(CvtArgs a) {
    int seg = blockIdx.y;
    const float* __restrict__ s = a.s[seg];
    u16* __restrict__ d = a.d[seg];
    int n = a.n[seg];
    for (int i = (blockIdx.x * 256 + threadIdx.x) * 4; i < n; i += gridDim.x * 1024) {
        float4 f = *(const float4*)&s[i];
        uint2 o;
        o.x = (u32)f2h_bits(f.x) | ((u32)f2h_bits(f.y) << 16);
        o.y = (u32)f2h_bits(f.z) | ((u32)f2h_bits(f.w) << 16);
        *(uint2*)&d[i] = o;
    }
}

// ---------------- QKV bt-GEMM: 128x128 tile. n<2048 -> f16 QK (stride 2048);
// n>=2048 -> V^T f16 OutVT[n-2048][4096]. grid (M/128, N/128): x=m so consecutive
// blocks share the same B-tile (per-XCD L2 locality). ----------------
__global__ __launch_bounds__(256) void gemm_qkv(
    const u16* __restrict__ A, const u16* __restrict__ B,
    u16* __restrict__ OutQK, u16* __restrict__ OutVT,
    const float* __restrict__ b0, const float* __restrict__ b1, const float* __restrict__ b2,
    int K) {
    __shared__ __align__(16) u16 As[128 * 32];
    __shared__ __align__(16) u16 Bs[128 * 32];
    const int tid = threadIdx.x;
    const int wid = tid >> 6, lid = tid & 63, quad = lid >> 4, l16 = lid & 15;
    const int wm = wid >> 1, wn = wid & 1;
    const int bm0 = blockIdx.x * 128, bn0 = blockIdx.y * 128;

    f32x4 acc[4][4] = {};
    const int sr = tid >> 2, sc = (tid & 3) * 8;   // LDS dest == tid*16B (lane-linear)

    for (int k0 = 0; k0 < K; k0 += 32) {
        __syncthreads();
        gld16(&A[(size_t)(bm0 + sr) * K + k0 + sc],      &As[tid * 8]);
        gld16(&A[(size_t)(bm0 + sr + 64) * K + k0 + sc], &As[2048 + tid * 8]);
        gld16(&B[(size_t)(bn0 + sr) * K + k0 + sc],      &Bs[tid * 8]);
        gld16(&B[(size_t)(bn0 + sr + 64) * K + k0 + sc], &Bs[2048 + tid * 8]);
        __syncthreads();
        f16x8 af[4], bf[4];
#pragma unroll
        for (int i = 0; i < 4; ++i) af[i] = *(const f16x8*)&As[(wm * 64 + i * 16 + l16) * 32 + quad * 8];
#pragma unroll
        for (int j = 0; j < 4; ++j) bf[j] = *(const f16x8*)&Bs[(wn * 64 + j * 16 + l16) * 32 + quad * 8];
#pragma unroll
        for (int i = 0; i < 4; ++i)
#pragma unroll
            for (int j = 0; j < 4; ++j)
                acc[i][j] = __builtin_amdgcn_mfma_f32_16x16x32_f16(af[i], bf[j], acc[i][j], 0, 0, 0);
    }

    const bool isV = (bn0 >= 2048);   // block-uniform
#pragma unroll
    for (int j = 0; j < 4; ++j) {
        int n = bn0 + wn * 64 + j * 16 + l16;
        float bias = (n < 1024) ? b0[n] : (n < 2048 ? b1[n - 1024] : b2[n - 2048]);
#pragma unroll
        for (int i = 0; i < 4; ++i) {
            int m0 = bm0 + wm * 64 + i * 16 + quad * 4;
            if (!isV) {
#pragma unroll
                for (int r = 0; r < 4; ++r)
                    OutQK[(size_t)(m0 + r) * 2048 + n] = f2h_bits(acc[i][j][r] + bias);
            } else {
                u16 h0 = f2h_bits(acc[i][j][0] + bias);
                u16 h1 = f2h_bits(acc[i][j][1] + bias);
                u16 h2 = f2h_bits(acc[i][j][2] + bias);
                u16 h3 = f2h_bits(acc[i][j][3] + bias);
                uint2 pk;
                pk.x = (u32)h0 | ((u32)h1 << 16);
                pk.y = (u32)h2 | ((u32)h3 << 16);
                *(uint2*)&OutVT[(size_t)(n - 2048) * 4096 + m0] = pk;
            }
        }
    }
}

// ---------------- final proj bt-GEMM: 128(M)x64(N) tile, f32 out + bias ----------------
// grid (M/128, N/64) = (32, 16): x=m for B-tile L2 locality.
__global__ __launch_bounds__(256) void gemm_n64(
    const u16* __restrict__ A, const u16* __restrict__ B, float* __restrict__ OutF,
    const float* __restrict__ bias, int N, int K) {
    __shared__ __align__(16) u16 As[128 * 32];
    __shared__ __align__(16) u16 Bs[64 * 32];
    const int tid = threadIdx.x;
    const int wid = tid >> 6, lid = tid & 63, quad = lid >> 4, l16 = lid & 15;
    const int bm0 = blockIdx.x * 128, bn0 = blockIdx.y * 64;

    f32x4 acc[2][4] = {};
    const int sr = tid >> 2, sc = (tid & 3) * 8;

    for (int k0 = 0; k0 < K; k0 += 32) {
        __syncthreads();
        gld16(&A[(size_t)(bm0 + sr) * K + k0 + sc],      &As[tid * 8]);
        gld16(&A[(size_t)(bm0 + sr + 64) * K + k0 + sc], &As[2048 + tid * 8]);
        gld16(&B[(size_t)(bn0 + sr) * K + k0 + sc],      &Bs[tid * 8]);
        __syncthreads();
        f16x8 af[2], bf[4];
#pragma unroll
        for (int i = 0; i < 2; ++i) af[i] = *(const f16x8*)&As[(wid * 32 + i * 16 + l16) * 32 + quad * 8];
#pragma unroll
        for (int j = 0; j < 4; ++j) bf[j] = *(const f16x8*)&Bs[(j * 16 + l16) * 32 + quad * 8];
#pragma unroll
        for (int i = 0; i < 2; ++i)
#pragma unroll
            for (int j = 0; j < 4; ++j)
                acc[i][j] = __builtin_amdgcn_mfma_f32_16x16x32_f16(af[i], bf[j], acc[i][j], 0, 0, 0);
    }

#pragma unroll
    for (int j = 0; j < 4; ++j) {
        int n = bn0 + j * 16 + l16;
        float bv = bias[n];
#pragma unroll
        for (int i = 0; i < 2; ++i) {
            int m0 = bm0 + wid * 32 + i * 16 + quad * 4;
#pragma unroll
            for (int r = 0; r < 4; ++r)
                OutF[(size_t)(m0 + r) * N + n] = acc[i][j][r] + bv;
        }
    }
}

// ---------------- windowed flash attention, S^T formulation, 8 waves x 16 q-rows ----------------
// log2-domain softmax (Q pre-scaled by log2e); pad chunks handled in closed form.
__global__ __launch_bounds__(512, 4) void attn_win(const u16* __restrict__ QK, const u16* __restrict__ VT,
                                                   u16* __restrict__ AO) {
    const int qt = blockIdx.x, w = blockIdx.y, h = blockIdx.z;
    const int tid = threadIdx.x, wid = tid >> 6, lid = tid & 63, quad = lid >> 4, l16 = lid & 15;

    __shared__ __align__(16) u16 Ks[2][64 * 32];   // [d-half][key][d32]
    __shared__ __align__(16) u16 Vt[2][64 * 36];   // [key-half][d][key32 + pad4]

    // Q frags (B-operand): B[n=q=l16][k=d = ks*32 + quad*8 + j], pre-scaled by log2(e)
    const int qrow = w * WSZ + qt * 128 + wid * 16 + l16;
    const _Float16 L2E = (_Float16)1.44269504f;
    f16x8 qf[2];
#pragma unroll
    for (int ks = 0; ks < 2; ++ks) {
        qf[ks] = *(const f16x8*)&QK[(size_t)qrow * 2048 + h * 64 + ks * 32 + quad * 8];
#pragma unroll
        for (int j = 0; j < 8; ++j) qf[ks][j] *= L2E;
    }

    // pad-key closed form: all pad keys have score -sum_d(q_d) (log2-scaled) and v = -1
    const int npad = (w == 0 || w == 7) ? 512 : 0;
    float s_p = 0.f;
    if (npad) {
        float sq = 0.f;
#pragma unroll
        for (int j = 0; j < 8; ++j) sq += (float)qf[0][j] + (float)qf[1][j];
        sq += __shfl_xor(sq, 16, 64);
        sq += __shfl_xor(sq, 32, 64);
        s_p = -sq;                 // per q = l16
    }

    f32x4 oacc[4] = {};
    float mrun = -30000.f;   // per q (= l16), log2 domain
    float lsum = 0.f;        // per-lane partial (this quad's keys)

    const int g0base = (w - 1) * WSZ;
    const int rqloc = qt * 128 + wid * 16 + l16;  // window-local q index of this lane
    const int rqw0 = qt * 128 + wid * 16;         // wave-uniform min q

    // staging maps (tid-based, computed once)
    const int kst = tid & 255, kkh = tid >> 8;        // K: key = kst>>2, col8 = (kst&3)*8
    const int vd = tid >> 3, vk0 = (tid & 7) * 8;     // V: d row, key group

    for (int c = 0; c < 24; ++c) {
        const int g0 = g0base + c * 64;
        if (g0 < 0 || g0 >= S) continue;                                 // pads: analytic
        if (!((c * 64 + 63 >= qt * 128) && (c * 64 <= qt * 128 + 1151))) continue;  // out of band

        __syncthreads();
        // K async global->LDS: 512 thr x 16B = 8KB
        gld16(QK + (size_t)(g0 + (kst >> 2)) * 2048 + 1024 + h * 64 + kkh * 32 + (kst & 3) * 8,
              &Ks[0][0] + kkh * 2048 + kst * 8);
        // V from VT: vector load + 2x ds_write_b64
        {
            uint4 va = *(const uint4*)(VT + (size_t)(h * 64 + vd) * 4096 + g0 + vk0);
            u16* vp = &Vt[vk0 >> 5][vd * 36 + (vk0 & 31)];
            *(uint2*)(vp)     = make_uint2(va.x, va.y);
            *(uint2*)(vp + 4) = make_uint2(va.z, va.w);
        }
        __syncthreads();

        // S^T = K * Q^T : lane holds S^T[key=nt*16+quad*4+r][q=l16]  (log2-scaled)
        f32x4 sc[4];
#pragma unroll
        for (int nt = 0; nt < 4; ++nt) {
            f16x8 kf0 = *(const f16x8*)&Ks[0][(nt * 16 + l16) * 32 + quad * 8];
            f16x8 kf1 = *(const f16x8*)&Ks[1][(nt * 16 + l16) * 32 + quad * 8];
            f32x4 t = {};
            t = __builtin_amdgcn_mfma_f32_16x16x32_f16(kf0, qf[0], t, 0, 0, 0);
            t = __builtin_amdgcn_mfma_f32_16x16x32_f16(kf1, qf[1], t, 0, 0, 0);
            sc[nt] = t;
        }

        // mask only when this wave's band edge intersects the chunk (wave-uniform branch)
        const bool needs_mask = (c * 64 < rqw0 + 16) || (c * 64 + 63 > rqw0 + 1024);
        if (needs_mask) {
#pragma unroll
            for (int nt = 0; nt < 4; ++nt)
#pragma unroll
                for (int r = 0; r < 4; ++r) {
                    int n = c * 64 + nt * 16 + quad * 4 + r;
                    if (n < rqloc || n > rqloc + 1024) sc[nt][r] = -30000.f;
                }
        }

        // online softmax (log2 domain)
        float mloc = mrun;
#pragma unroll
        for (int nt = 0; nt < 4; ++nt)
            mloc = fmaxf(mloc, fmaxf(fmaxf(sc[nt][0], sc[nt][1]), fmaxf(sc[nt][2], sc[nt][3])));
        mloc = fmaxf(mloc, __shfl_xor(mloc, 16, 64));
        mloc = fmaxf(mloc, __shfl_xor(mloc, 32, 64));

        const bool up = __any(mloc > mrun);
        float ls = 0.f;
        f16x4 pf[4];
#pragma unroll
        for (int nt = 0; nt < 4; ++nt)
#pragma unroll
            for (int r = 0; r < 4; ++r) {
                float p = exp2f(sc[nt][r] - mloc);
                ls += p;
                pf[nt][r] = (_Float16)p;
            }
        if (up) {
            float alpha = exp2f(mrun - mloc);
            mrun = mloc;
            lsum = lsum * alpha + ls;
            float ao[4];
#pragma unroll
            for (int r = 0; r < 4; ++r) ao[r] = __shfl(alpha, quad * 4 + r, 64);
#pragma unroll
            for (int dt = 0; dt < 4; ++dt)
#pragma unroll
                for (int r = 0; r < 4; ++r) oacc[dt][r] *= ao[r];
        } else {
            lsum += ls;
        }

        // O += P V  (P direct from regs as A-operand of 16x16x16)
#pragma unroll
        for (int nt = 0; nt < 4; ++nt)
#pragma unroll
            for (int dt = 0; dt < 4; ++dt) {
                f16x4 vf = *(const f16x4*)&Vt[nt >> 1][(dt * 16 + l16) * 36 + (nt & 1) * 16 + quad * 4];
                oacc[dt] = __builtin_amdgcn_mfma_f32_16x16x16f16(pf[nt], vf, oacc[dt], 0, 0, 0);
            }
    }

    // epilogue: reduce l across quads, fold pad contribution, normalize, store f16
    float lt = lsum;
    lt += __shfl_xor(lt, 16, 64);
    lt += __shfl_xor(lt, 32, 64);          // per q = l16, real keys only
    float aW = 1.f, pw = 0.f;
    if (npad) {
        float mnew = fmaxf(mrun, s_p);
        aW = exp2f(mrun - mnew);
        pw = 512.f * exp2f(s_p - mnew);    // total pad weight
        lt = lt * aW + pw;
    }
    float linv = 1.f / lt;
    float lrec[4], arow[4], pwrow[4];
#pragma unroll
    for (int r = 0; r < 4; ++r) {
        lrec[r]  = __shfl(linv, quad * 4 + r, 64);
        arow[r]  = __shfl(aW,   quad * 4 + r, 64);
        pwrow[r] = __shfl(pw,   quad * 4 + r, 64);
    }
#pragma unroll
    for (int dt = 0; dt < 4; ++dt)
#pragma unroll
        for (int r = 0; r < 4; ++r) {
            int srow = w * WSZ + qt * 128 + wid * 16 + quad * 4 + r;
            int col = h * 64 + dt * 16 + l16;
            float o = (oacc[dt][r] * arow[r] - pwrow[r]) * lrec[r];   // pad v = -1 every dim
            AO[(size_t)srow * E + col] = f2h_bits(o);
        }
}

// ---------------- launch ----------------
extern "C" void kernel_launch(void* const* d_in, const int* in_sizes, int n_in,
                              void* d_out, int out_size, void* d_ws, size_t ws_size,
                              hipStream_t stream) {
    const float* x  = (const float*)d_in[0];
    const float* wq = (const float*)d_in[1];
    const float* bq = (const float*)d_in[2];
    const float* wk = (const float*)d_in[3];
    const float* bk = (const float*)d_in[4];
    const float* wv = (const float*)d_in[5];
    const float* bv = (const float*)d_in[6];
    const float* wo = (const float*)d_in[7];
    const float* bo = (const float*)d_in[8];
    float* out = (float*)d_out;

    char* ws = (char*)d_ws;
    u16* XH  = (u16*)(ws);               // 4096x1024 f16   [0, 8388608)
    u16* WC  = (u16*)(ws + 8388608);     // 3072x1024 f16   [8388608, 14680064)
    u16* WOh = (u16*)(ws + 14680064);    // 1024x1024 f16   [14680064, 16777216)
    u16* QK  = (u16*)(ws + 16777216);    // 4096x2048 f16   [16777216, 33554432)
    u16* VTg = (u16*)(ws + 33554432);    // 1024x4096 f16   [33554432, 41943040)
    u16* AOh = (u16*)(ws + 41943040);    // 4096x1024 f16   [41943040, 50331648)

    CvtArgs ca;
    ca.s[0] = x;  ca.d[0] = XH;            ca.n[0] = 4194304;
    ca.s[1] = wq; ca.d[1] = WC;            ca.n[1] = 1048576;
    ca.s[2] = wk; ca.d[2] = WC + 1048576;  ca.n[2] = 1048576;
    ca.s[3] = wv; ca.d[3] = WC + 2097152;  ca.n[3] = 1048576;
    ca.s[4] = wo; ca.d[4] = WOh;           ca.n[4] = 1048576;
    cvt5<<<dim3(1024, 5), 256, 0, stream>>>(ca);

    gemm_qkv<<<dim3(32, 24), 256, 0, stream>>>(XH, WC, QK, VTg, bq, bk, bv, 1024);
    attn_win<<<dim3(4, 8, 16), 512, 0, stream>>>(QK, VTg, AOh);
    gemm_n64<<<dim3(32, 16), 256, 0, stream>>>(AOh, WOh, out, bo, 1024, 1024);
}

// Round 6
// 196.542 us; speedup vs baseline: 1.5111x; 1.0077x over previous
//
#include <hip/hip_runtime.h>
#include <stdint.h>

#define S 4096
#define E 1024
#define NH 16
#define HD 64
#define WSZ 512

typedef _Float16 f16x8 __attribute__((ext_vector_type(8)));
typedef _Float16 f16x4 __attribute__((ext_vector_type(4)));
typedef float f32x4 __attribute__((ext_vector_type(4)));
typedef unsigned short u16;
typedef unsigned int u32;

__device__ __forceinline__ u16 f2h_bits(float f) {
    union { _Float16 h; u16 u; } cv; cv.h = (_Float16)f; return cv.u;
}

__device__ __forceinline__ void gld16(const u16* g, u16* l) {
    __builtin_amdgcn_global_load_lds((const __attribute__((address_space(1))) void*)g,
                                     (__attribute__((address_space(3))) void*)l, 16, 0, 0);
}

// ---------------- fused fp32->fp16 converts (5 segments, 1 launch) ----------------
struct CvtArgs {
    const float* s[5];
    u16* d[5];
    int n[5];
};
__global__ void cvt5(CvtArgs a) {
    int seg = blockIdx.y;
    const float* __restrict__ s = a.s[seg];
    u16* __restrict__ d = a.d[seg];
    int n = a.n[seg];
    for (int i = (blockIdx.x * 256 + threadIdx.x) * 4; i < n; i += gridDim.x * 1024) {
        float4 f = *(const float4*)&s[i];
        uint2 o;
        o.x = (u32)f2h_bits(f.x) | ((u32)f2h_bits(f.y) << 16);
        o.y = (u32)f2h_bits(f.z) | ((u32)f2h_bits(f.w) << 16);
        *(uint2*)&d[i] = o;
    }
}

// ---------------- QKV bt-GEMM: 128x128 tile. n<2048 -> f16 QK (stride 2048);
// n>=2048 -> V^T f16 OutVT[n-2048][4096]. grid (M/128, N/128): x=m for B-tile L2 locality. ----------------
__global__ __launch_bounds__(256) void gemm_qkv(
    const u16* __restrict__ A, const u16* __restrict__ B,
    u16* __restrict__ OutQK, u16* __restrict__ OutVT,
    const float* __restrict__ b0, const float* __restrict__ b1, const float* __restrict__ b2,
    int K) {
    __shared__ __align__(16) u16 As[128 * 32];
    __shared__ __align__(16) u16 Bs[128 * 32];
    const int tid = threadIdx.x;
    const int wid = tid >> 6, lid = tid & 63, quad = lid >> 4, l16 = lid & 15;
    const int wm = wid >> 1, wn = wid & 1;
    const int bm0 = blockIdx.x * 128, bn0 = blockIdx.y * 128;

    f32x4 acc[4][4] = {};
    const int sr = tid >> 2, sc = (tid & 3) * 8;   // LDS dest == tid*16B (lane-linear)

    for (int k0 = 0; k0 < K; k0 += 32) {
        __syncthreads();
        gld16(&A[(size_t)(bm0 + sr) * K + k0 + sc],      &As[tid * 8]);
        gld16(&A[(size_t)(bm0 + sr + 64) * K + k0 + sc], &As[2048 + tid * 8]);
        gld16(&B[(size_t)(bn0 + sr) * K + k0 + sc],      &Bs[tid * 8]);
        gld16(&B[(size_t)(bn0 + sr + 64) * K + k0 + sc], &Bs[2048 + tid * 8]);
        __syncthreads();
        f16x8 af[4], bf[4];
#pragma unroll
        for (int i = 0; i < 4; ++i) af[i] = *(const f16x8*)&As[(wm * 64 + i * 16 + l16) * 32 + quad * 8];
#pragma unroll
        for (int j = 0; j < 4; ++j) bf[j] = *(const f16x8*)&Bs[(wn * 64 + j * 16 + l16) * 32 + quad * 8];
#pragma unroll
        for (int i = 0; i < 4; ++i)
#pragma unroll
            for (int j = 0; j < 4; ++j)
                acc[i][j] = __builtin_amdgcn_mfma_f32_16x16x32_f16(af[i], bf[j], acc[i][j], 0, 0, 0);
    }

    const bool isV = (bn0 >= 2048);   // block-uniform
#pragma unroll
    for (int j = 0; j < 4; ++j) {
        int n = bn0 + wn * 64 + j * 16 + l16;
        float bias = (n < 1024) ? b0[n] : (n < 2048 ? b1[n - 1024] : b2[n - 2048]);
#pragma unroll
        for (int i = 0; i < 4; ++i) {
            int m0 = bm0 + wm * 64 + i * 16 + quad * 4;
            if (!isV) {
#pragma unroll
                for (int r = 0; r < 4; ++r)
                    OutQK[(size_t)(m0 + r) * 2048 + n] = f2h_bits(acc[i][j][r] + bias);
            } else {
                u16 h0 = f2h_bits(acc[i][j][0] + bias);
                u16 h1 = f2h_bits(acc[i][j][1] + bias);
                u16 h2 = f2h_bits(acc[i][j][2] + bias);
                u16 h3 = f2h_bits(acc[i][j][3] + bias);
                uint2 pk;
                pk.x = (u32)h0 | ((u32)h1 << 16);
                pk.y = (u32)h2 | ((u32)h3 << 16);
                *(uint2*)&OutVT[(size_t)(n - 2048) * 4096 + m0] = pk;
            }
        }
    }
}

// ---------------- final proj bt-GEMM: 128(M)x64(N) tile, f32 out + bias ----------------
__global__ __launch_bounds__(256) void gemm_n64(
    const u16* __restrict__ A, const u16* __restrict__ B, float* __restrict__ OutF,
    const float* __restrict__ bias, int N, int K) {
    __shared__ __align__(16) u16 As[128 * 32];
    __shared__ __align__(16) u16 Bs[64 * 32];
    const int tid = threadIdx.x;
    const int wid = tid >> 6, lid = tid & 63, quad = lid >> 4, l16 = lid & 15;
    const int bm0 = blockIdx.x * 128, bn0 = blockIdx.y * 64;

    f32x4 acc[2][4] = {};
    const int sr = tid >> 2, sc = (tid & 3) * 8;

    for (int k0 = 0; k0 < K; k0 += 32) {
        __syncthreads();
        gld16(&A[(size_t)(bm0 + sr) * K + k0 + sc],      &As[tid * 8]);
        gld16(&A[(size_t)(bm0 + sr + 64) * K + k0 + sc], &As[2048 + tid * 8]);
        gld16(&B[(size_t)(bn0 + sr) * K + k0 + sc],      &Bs[tid * 8]);
        __syncthreads();
        f16x8 af[2], bf[4];
#pragma unroll
        for (int i = 0; i < 2; ++i) af[i] = *(const f16x8*)&As[(wid * 32 + i * 16 + l16) * 32 + quad * 8];
#pragma unroll
        for (int j = 0; j < 4; ++j) bf[j] = *(const f16x8*)&Bs[(j * 16 + l16) * 32 + quad * 8];
#pragma unroll
        for (int i = 0; i < 2; ++i)
#pragma unroll
            for (int j = 0; j < 4; ++j)
                acc[i][j] = __builtin_amdgcn_mfma_f32_16x16x32_f16(af[i], bf[j], acc[i][j], 0, 0, 0);
    }

#pragma unroll
    for (int j = 0; j < 4; ++j) {
        int n = bn0 + j * 16 + l16;
        float bv = bias[n];
#pragma unroll
        for (int i = 0; i < 2; ++i) {
            int m0 = bm0 + wid * 32 + i * 16 + quad * 4;
#pragma unroll
            for (int r = 0; r < 4; ++r)
                OutF[(size_t)(m0 + r) * N + n] = acc[i][j][r] + bv;
        }
    }
}

// ---------------- windowed flash attention: S^T form, log2 softmax, analytic pads,
// double-buffered K/V staging (prefetch chunk c+1 during compute of c, 1 barrier/chunk) ----------------
__global__ __launch_bounds__(512, 4) void attn_win(const u16* __restrict__ QK, const u16* __restrict__ VT,
                                                   u16* __restrict__ AO) {
    const int qt = blockIdx.x, w = blockIdx.y, h = blockIdx.z;
    const int tid = threadIdx.x, wid = tid >> 6, lid = tid & 63, quad = lid >> 4, l16 = lid & 15;

    __shared__ __align__(16) u16 Ks[2][2 * 64 * 32];   // [buf][d-half][key][d32]
    __shared__ __align__(16) u16 Vt[2][2 * 64 * 36];   // [buf][key-half][d][key32+pad4]

    // Q frags (B-operand), pre-scaled by log2(e)
    const int qrow = w * WSZ + qt * 128 + wid * 16 + l16;
    const _Float16 L2E = (_Float16)1.44269504f;
    f16x8 qf[2];
#pragma unroll
    for (int ks = 0; ks < 2; ++ks) {
        qf[ks] = *(const f16x8*)&QK[(size_t)qrow * 2048 + h * 64 + ks * 32 + quad * 8];
#pragma unroll
        for (int j = 0; j < 8; ++j) qf[ks][j] *= L2E;
    }

    // pad-key closed form: all pad keys score -sum_d(q_d) (log2-scaled), v = -1
    const int npad = (w == 0 || w == 7) ? 512 : 0;
    float s_p = 0.f;
    if (npad) {
        float sq = 0.f;
#pragma unroll
        for (int j = 0; j < 8; ++j) sq += (float)qf[0][j] + (float)qf[1][j];
        sq += __shfl_xor(sq, 16, 64);
        sq += __shfl_xor(sq, 32, 64);
        s_p = -sq;
    }

    f32x4 oacc[4] = {};
    float mrun = -30000.f;
    float lsum = 0.f;

    const int g0base = (w - 1) * WSZ;
    const int rqloc = qt * 128 + wid * 16 + l16;
    const int rqw0 = qt * 128 + wid * 16;

    // contiguous chunk range: band [2qt, 2qt+17] ∩ real [(1-w)*8, 71-8w] ∩ [0,23]
    int cfirst = 2 * qt; if ((1 - w) * 8 > cfirst) cfirst = (1 - w) * 8;
    int clast = 2 * qt + 17; if (71 - 8 * w < clast) clast = 71 - 8 * w; if (clast > 23) clast = 23;

    // staging maps
    const int kst = tid & 255, kkh = tid >> 8;        // K: key = kst>>2, col8 = (kst&3)*8
    const int vd = tid >> 3, vk0 = (tid & 7) * 8;     // V: d row, key group
    const size_t kgoff = 1024 + h * 64 + kkh * 32 + (kst & 3) * 8 + (size_t)(kst >> 2) * 2048;
    const int kloff = kkh * 2048 + kst * 8;
    const u16* vgrow = VT + (size_t)(h * 64 + vd) * 4096 + vk0;
    const int vloff = (vk0 >> 5) * 2304 + vd * 36 + (vk0 & 31);

    // stage first chunk into buf 0
    {
        const int g0 = g0base + cfirst * 64;
        uint4 va = *(const uint4*)(vgrow + g0);
        gld16(QK + (size_t)g0 * 2048 + kgoff, &Ks[0][0] + kloff);
        u16* vp = &Vt[0][0] + vloff;
        *(uint2*)(vp)     = make_uint2(va.x, va.y);
        *(uint2*)(vp + 4) = make_uint2(va.z, va.w);
    }

    int ib = 0;
    for (int c = cfirst; c <= clast; ++c, ib ^= 1) {
        __syncthreads();   // stage(c -> ib) complete; compute(c-1) on ib^1 done everywhere

        const bool has_next = (c < clast);
        uint4 vnext;
        if (has_next) {
            const int gn = g0base + (c + 1) * 64;
            vnext = *(const uint4*)(vgrow + gn);                       // VGPR prefetch
            gld16(QK + (size_t)gn * 2048 + kgoff, &Ks[ib ^ 1][0] + kloff);  // async K -> other buf
        }

        const u16* KsB = &Ks[ib][0];
        const u16* VtB = &Vt[ib][0];

        // S^T = K * Q^T : lane holds S^T[key=nt*16+quad*4+r][q=l16]  (log2-scaled)
        f32x4 sc[4];
#pragma unroll
        for (int nt = 0; nt < 4; ++nt) {
            f16x8 kf0 = *(const f16x8*)&KsB[(nt * 16 + l16) * 32 + quad * 8];
            f16x8 kf1 = *(const f16x8*)&KsB[2048 + (nt * 16 + l16) * 32 + quad * 8];
            f32x4 t = {};
            t = __builtin_amdgcn_mfma_f32_16x16x32_f16(kf0, qf[0], t, 0, 0, 0);
            t = __builtin_amdgcn_mfma_f32_16x16x32_f16(kf1, qf[1], t, 0, 0, 0);
            sc[nt] = t;
        }

        // mask only when this wave's band edge intersects the chunk (wave-uniform)
        const bool needs_mask = (c * 64 < rqw0 + 16) || (c * 64 + 63 > rqw0 + 1024);
        if (needs_mask) {
#pragma unroll
            for (int nt = 0; nt < 4; ++nt)
#pragma unroll
                for (int r = 0; r < 4; ++r) {
                    int n = c * 64 + nt * 16 + quad * 4 + r;
                    if (n < rqloc || n > rqloc + 1024) sc[nt][r] = -30000.f;
                }
        }

        // online softmax (log2 domain), conditional rescale
        float mloc = mrun;
#pragma unroll
        for (int nt = 0; nt < 4; ++nt)
            mloc = fmaxf(mloc, fmaxf(fmaxf(sc[nt][0], sc[nt][1]), fmaxf(sc[nt][2], sc[nt][3])));
        mloc = fmaxf(mloc, __shfl_xor(mloc, 16, 64));
        mloc = fmaxf(mloc, __shfl_xor(mloc, 32, 64));

        const bool up = __any(mloc > mrun);
        float ls = 0.f;
        f16x4 pf[4];
#pragma unroll
        for (int nt = 0; nt < 4; ++nt)
#pragma unroll
            for (int r = 0; r < 4; ++r) {
                float p = exp2f(sc[nt][r] - mloc);
                ls += p;
                pf[nt][r] = (_Float16)p;
            }
        if (up) {
            float alpha = exp2f(mrun - mloc);
            mrun = mloc;
            lsum = lsum * alpha + ls;
            float ao[4];
#pragma unroll
            for (int r = 0; r < 4; ++r) ao[r] = __shfl(alpha, quad * 4 + r, 64);
#pragma unroll
            for (int dt = 0; dt < 4; ++dt)
#pragma unroll
                for (int r = 0; r < 4; ++r) oacc[dt][r] *= ao[r];
        } else {
            lsum += ls;
        }

        // O += P V  (P direct from regs as A-operand of 16x16x16)
#pragma unroll
        for (int nt = 0; nt < 4; ++nt)
#pragma unroll
            for (int dt = 0; dt < 4; ++dt) {
                f16x4 vf = *(const f16x4*)&VtB[(nt >> 1) * 2304 + (dt * 16 + l16) * 36 + (nt & 1) * 16 + quad * 4];
                oacc[dt] = __builtin_amdgcn_mfma_f32_16x16x16f16(pf[nt], vf, oacc[dt], 0, 0, 0);
            }

        // park prefetched V into the other buffer
        if (has_next) {
            u16* vp = &Vt[ib ^ 1][0] + vloff;
            *(uint2*)(vp)     = make_uint2(vnext.x, vnext.y);
            *(uint2*)(vp + 4) = make_uint2(vnext.z, vnext.w);
        }
    }

    // epilogue: reduce l across quads, fold pad contribution, normalize, store f16
    float lt = lsum;
    lt += __shfl_xor(lt, 16, 64);
    lt += __shfl_xor(lt, 32, 64);
    float aW = 1.f, pw = 0.f;
    if (npad) {
        float mnew = fmaxf(mrun, s_p);
        aW = exp2f(mrun - mnew);
        pw = 512.f * exp2f(s_p - mnew);
        lt = lt * aW + pw;
    }
    float linv = 1.f / lt;
    float lrec[4], arow[4], pwrow[4];
#pragma unroll
    for (int r = 0; r < 4; ++r) {
        lrec[r]  = __shfl(linv, quad * 4 + r, 64);
        arow[r]  = __shfl(aW,   quad * 4 + r, 64);
        pwrow[r] = __shfl(pw,   quad * 4 + r, 64);
    }
#pragma unroll
    for (int dt = 0; dt < 4; ++dt)
#pragma unroll
        for (int r = 0; r < 4; ++r) {
            int srow = w * WSZ + qt * 128 + wid * 16 + quad * 4 + r;
            int col = h * 64 + dt * 16 + l16;
            float o = (oacc[dt][r] * arow[r] - pwrow[r]) * lrec[r];   // pad v = -1 every dim
            AO[(size_t)srow * E + col] = f2h_bits(o);
        }
}

// ---------------- launch ----------------
extern "C" void kernel_launch(void* const* d_in, const int* in_sizes, int n_in,
                              void* d_out, int out_size, void* d_ws, size_t ws_size,
                              hipStream_t stream) {
    const float* x  = (const float*)d_in[0];
    const float* wq = (const float*)d_in[1];
    const float* bq = (const float*)d_in[2];
    const float* wk = (const float*)d_in[3];
    const float* bk = (const float*)d_in[4];
    const float* wv = (const float*)d_in[5];
    const float* bv = (const float*)d_in[6];
    const float* wo = (const float*)d_in[7];
    const float* bo = (const float*)d_in[8];
    float* out = (float*)d_out;

    char* ws = (char*)d_ws;
    u16* XH  = (u16*)(ws);               // 4096x1024 f16   [0, 8388608)
    u16* WC  = (u16*)(ws + 8388608);     // 3072x1024 f16   [8388608, 14680064)
    u16* WOh = (u16*)(ws + 14680064);    // 1024x1024 f16   [14680064, 16777216)
    u16* QK  = (u16*)(ws + 16777216);    // 4096x2048 f16   [16777216, 33554432)
    u16* VTg = (u16*)(ws + 33554432);    // 1024x4096 f16   [33554432, 41943040)
    u16* AOh = (u16*)(ws + 41943040);    // 4096x1024 f16   [41943040, 50331648)

    CvtArgs ca;
    ca.s[0] = x;  ca.d[0] = XH;            ca.n[0] = 4194304;
    ca.s[1] = wq; ca.d[1] = WC;            ca.n[1] = 1048576;
    ca.s[2] = wk; ca.d[2] = WC + 1048576;  ca.n[2] = 1048576;
    ca.s[3] = wv; ca.d[3] = WC + 2097152;  ca.n[3] = 1048576;
    ca.s[4] = wo; ca.d[4] = WOh;           ca.n[4] = 1048576;
    cvt5<<<dim3(1024, 5), 256, 0, stream>>>(ca);

    gemm_qkv<<<dim3(32, 24), 256, 0, stream>>>(XH, WC, QK, VTg, bq, bk, bv, 1024);
    attn_win<<<dim3(4, 8, 16), 512, 0, stream>>>(QK, VTg, AOh);
    gemm_n64<<<dim3(32, 16), 256, 0, stream>>>(AOh, WOh, out, bo, 1024, 1024);
}